// Round 6
// baseline (473.194 us; speedup 1.0000x reference)
//
#include <hip/hip_runtime.h>
#include <hip/hip_bf16.h>
#include <math.h>

#define NB 4
#define NN 128
#define NF 128
#define NS 5
#define NT 32
#define NL 2

typedef __hip_bfloat16 bf16;

__device__ __forceinline__ float b2f(const bf16 x) { return __bfloat162float(x); }
__device__ __forceinline__ float silu_f(float x) { return x / (1.0f + expf(-x)); }

#define PI_F 3.14159265358979323846f
#define SQRT3_F 1.7320508075688772f

// converted-weights region offsets (floats) within d_ws after the flag slot
#define POS_OFF 0
#define GF_OFF  1536
#define WE_OFF  1664
#define BE_OFF  6400
#define WR1_OFF 6528
#define BR1_OFF 6656
#define WR2_OFF 6784
#define WN_OFF  72320
#define C1_OFF  105088
#define C2_OFF  106112
#define C3_OFF  107136
#define M0_OFF  108160
#define M1_OFF  140928
#define G1_OFF  173696
#define G2_OFF  177792
#define WV_OFF  181888
#define CVT_TOTAL 182144

// ---------------------------------------------------------------------------
// convert (+ fused detect): each block locally decides bf16 vs f32 from the
// positions array, then converts its slice of all float inputs to f32.
// ---------------------------------------------------------------------------
__global__ void convert_kernel(
    const void* __restrict__ pos, const void* __restrict__ gf,
    const void* __restrict__ we,  const void* __restrict__ be,
    const void* __restrict__ wr1, const void* __restrict__ br1,
    const void* __restrict__ wr2, const void* __restrict__ wn,
    const void* __restrict__ c1,  const void* __restrict__ c2,
    const void* __restrict__ c3,  const void* __restrict__ m0,
    const void* __restrict__ m1,  const void* __restrict__ g1,
    const void* __restrict__ g2,  const void* __restrict__ wv,
    int* __restrict__ flag, float* __restrict__ dst)
{
  __shared__ int sbad;
  const int tid = threadIdx.x;
  if (tid == 0) sbad = 0;
  __syncthreads();
  {
    const bf16* p = (const bf16*)pos;
    int bad = 0;
    for (int i = tid; i < NB*NN*3; i += blockDim.x) {
      float v = b2f(p[i]);
      if (!(fabsf(v) <= 1024.0f)) bad = 1;   // NaN also fails
    }
    if (bad) sbad = 1;
  }
  __syncthreads();
  const int fl = sbad ? 0 : 1;               // 1 = bf16 inputs
  if (blockIdx.x == 0 && tid == 0) *flag = fl;

  const int stride = gridDim.x * blockDim.x;
  for (int i = blockIdx.x * blockDim.x + tid; i < CVT_TOTAL; i += stride) {
    const void* src; int j;
    if      (i < GF_OFF)  { src = pos; j = i - POS_OFF; }
    else if (i < WE_OFF)  { src = gf;  j = i - GF_OFF; }
    else if (i < BE_OFF)  { src = we;  j = i - WE_OFF; }
    else if (i < WR1_OFF) { src = be;  j = i - BE_OFF; }
    else if (i < BR1_OFF) { src = wr1; j = i - WR1_OFF; }
    else if (i < WR2_OFF) { src = br1; j = i - BR1_OFF; }
    else if (i < WN_OFF)  { src = wr2; j = i - WR2_OFF; }
    else if (i < C1_OFF)  { src = wn;  j = i - WN_OFF; }
    else if (i < C2_OFF)  { src = c1;  j = i - C1_OFF; }
    else if (i < C3_OFF)  { src = c2;  j = i - C2_OFF; }
    else if (i < M0_OFF)  { src = c3;  j = i - C3_OFF; }
    else if (i < M1_OFF)  { src = m0;  j = i - M0_OFF; }
    else if (i < G1_OFF)  { src = m1;  j = i - M1_OFF; }
    else if (i < G2_OFF)  { src = g1;  j = i - G1_OFF; }
    else if (i < WV_OFF)  { src = g2;  j = i - G2_OFF; }
    else                  { src = wv;  j = i - WV_OFF; }
    dst[i] = fl ? b2f(((const bf16*)src)[j]) : ((const float*)src)[j];
  }
}

// ---------------------------------------------------------------------------
// prep: env row, scal row (LDS only), z layer-0, vec=0, pos_cur, Ag=0.
// ---------------------------------------------------------------------------
__global__ void prep_kernel(
    const float* __restrict__ cvt, const int* __restrict__ nfeat,
    float* __restrict__ pos_cur, float* __restrict__ z,
    float* __restrict__ vec, float* __restrict__ env,
    float* __restrict__ Ag)
{
  const int bn = blockIdx.x;        // b*NN + n
  const int b  = bn >> 7;
  const int n  = bn & 127;
  const int f  = threadIdx.x;       // 0..127
  __shared__ float posB[NN*3];
  __shared__ float scs[NF];

  for (int i = f; i < NN*3; i += 128)
    posB[i] = cvt[POS_OFF + b*NN*3 + i];

  // scal row (LDS only)
  {
    int sp = nfeat[bn] - 1;
    float acc = cvt[WE_OFF + sp*NF + f] + cvt[BE_OFF + f];
    #pragma unroll 8
    for (int t = 0; t < NT; ++t)
      acc += cvt[GF_OFF + b*NT + t] * cvt[WE_OFF + (NS + t)*NF + f];
    scs[f] = acc;
  }
  __syncthreads();

  // env row (from initial positions)
  {
    float px = posB[n*3+0], py = posB[n*3+1], pz = posB[n*3+2];
    int s = f;
    float vx = px - posB[s*3+0];
    float vy = py - posB[s*3+1];
    float vz = pz - posB[s*3+2];
    float lng = sqrtf(vx*vx + vy*vy + vz*vz + 1e-12f);
    env[bn*NN + s] = (lng < 10.0f) ? 0.5f*(cosf(PI_F*lng*0.1f) + 1.0f) : 0.0f;
  }

  // z for layer 0
  {
    const float* W = cvt + WN_OFF;   // layer 0
    float acc = 0.f;
    #pragma unroll 8
    for (int k = 0; k < NF; ++k)
      acc += scs[k] * W[k*NF + f];
    z[bn*NF + f] = acc;
  }

  // vec = 0, Ag = 0
  vec[((size_t)bn*3 + 0)*NF + f] = 0.f;
  vec[((size_t)bn*3 + 1)*NF + f] = 0.f;
  vec[((size_t)bn*3 + 2)*NF + f] = 0.f;
  float* Arow = Ag + (size_t)bn*4*NF;
  #pragma unroll
  for (int c = 0; c < 4; ++c) Arow[c*NF + f] = 0.f;

  if (f < 3) pos_cur[bn*3 + f] = posB[n*3 + f];
}

// ---------------------------------------------------------------------------
// EDGE v4: grid = NB*32*8 = 1024 blocks (b, 4-receiver tile, 16-sender group)
// 256 threads = (p = h-half, fo = column). Both ell0/ell1 Wr2 columns in
// registers. 4 blocks/CU (launch_bounds 256,4). Raw partial A via atomicAdd.
// ---------------------------------------------------------------------------
__global__ __launch_bounds__(256, 4)
void edge_kernel(const float* __restrict__ pos_cur,
                 const float* __restrict__ z,
                 const float* __restrict__ vec,
                 const float* __restrict__ env,
                 const float* __restrict__ cvt,
                 int layer, float* __restrict__ Ag)
{
  __shared__ float posL[NN*3];                 // 1.5 KB
  __shared__ float envL[4][16];                // this sender group
  __shared__ float w1L[64], b1L[64];
  __shared__ float zvL[4][4][NF];              // 8 KB
  __shared__ __align__(16) float hidL[4][64][4]; // 4 KB
  __shared__ __align__(16) float4 uenvL[4][4];
  __shared__ float combL[16][NF];              // 8 KB

  const int tid  = threadIdx.x;
  const int bidx = blockIdx.x;                 // b*256 + rt*8 + sg
  const int b    = bidx >> 8;
  const int rt   = (bidx >> 3) & 31;
  const int sg   = bidx & 7;
  const int r0   = rt * 4;
  const int sbase= sg * 16;
  const int p    = tid >> 7;
  const int fo   = tid & 127;

  for (int i = tid; i < NN*3; i += 256)
    posL[i] = pos_cur[b*NN*3 + i];
  if (tid < 64) {
    int rr = tid >> 4, j = tid & 15;
    envL[rr][j] = env[(b*NN + r0 + rr)*NN + sbase + j];
    w1L[tid] = cvt[WR1_OFF + layer*64 + tid];
    b1L[tid] = cvt[BR1_OFF + layer*64 + tid];
  }
  // Wr2 columns for both halves into registers
  float wA[32], wB[32];
  {
    const float* W2 = cvt + WR2_OFF + layer*64*512;
    #pragma unroll
    for (int hh = 0; hh < 32; ++hh) {
      wA[hh] = W2[(p*32 + hh)*512 + fo];        // ell0 column
      wB[hh] = W2[(p*32 + hh)*512 + 128 + fo];  // ell1 column
    }
  }
  float ac[4][4];
  #pragma unroll
  for (int c = 0; c < 4; ++c)
    #pragma unroll
    for (int r = 0; r < 4; ++r) ac[c][r] = 0.f;

  __syncthreads();

  const int rme = tid >> 6;
  const int hme = tid & 63;
  const float hrx = posL[(r0 + rme)*3 + 0];
  const float hry = posL[(r0 + rme)*3 + 1];
  const float hrz = posL[(r0 + rme)*3 + 2];
  const float w1v = w1L[hme], b1v = b1L[hme];

  for (int c0 = 0; c0 < 16; c0 += 4) {
    // ---- issue global loads first (hide under LDS math below) ----
    float stg[8];
    #pragma unroll
    for (int j = 0; j < 8; ++j) {
      int i = tid + j*256;
      int s = i >> 9, row = (i >> 7) & 3;
      int c = i & 127;
      int gs = b*NN + sbase + c0 + s;
      stg[j] = (row == 0) ? z[gs*NF + c]
                          : vec[((size_t)gs*3 + row - 1)*NF + c];
    }
    // ---- radial-hidden (LDS-only math) ----
    {
      float hv[4];
      #pragma unroll
      for (int si = 0; si < 4; ++si) {
        int s = sbase + c0 + si;
        float vx = hrx - posL[s*3 + 0];
        float vy = hry - posL[s*3 + 1];
        float vz = hrz - posL[s*3 + 2];
        float lng = sqrtf(vx*vx + vy*vy + vz*vz + 1e-12f);
        hv[si] = silu_f(lng * w1v + b1v);
      }
      *(float4*)&hidL[rme][hme][0] = make_float4(hv[0], hv[1], hv[2], hv[3]);
    }
    if (tid < 16) {
      int r = tid >> 2, si = tid & 3;
      int s = sbase + c0 + si;
      float vx = posL[(r0 + r)*3 + 0] - posL[s*3 + 0];
      float vy = posL[(r0 + r)*3 + 1] - posL[s*3 + 1];
      float vz = posL[(r0 + r)*3 + 2] - posL[s*3 + 2];
      float lng = sqrtf(vx*vx + vy*vy + vz*vz + 1e-12f);
      float inv = 1.0f / lng;
      float envw = (s == r0 + r) ? 0.f : envL[r][c0 + si] * 0.0625f;
      uenvL[r][si] = make_float4(vx*inv, vy*inv, vz*inv, envw);
    }
    // ---- commit staged z/vec to LDS ----
    #pragma unroll
    for (int j = 0; j < 8; ++j) {
      int i = tid + j*256;
      int s = i >> 9, row = (i >> 7) & 3, c = i & 127;
      zvL[s][row][c] = stg[j];
    }
    __syncthreads();

    // ---- rw partial dots (both column-halves per thread) ----
    float rwA[4][4], rwB[4][4];
    #pragma unroll
    for (int r = 0; r < 4; ++r)
      #pragma unroll
      for (int si = 0; si < 4; ++si) { rwA[r][si] = 0.f; rwB[r][si] = 0.f; }
    #pragma unroll
    for (int hh = 0; hh < 32; ++hh) {
      float a = wA[hh], bb = wB[hh];
      int h = p*32 + hh;
      #pragma unroll
      for (int r = 0; r < 4; ++r) {
        float4 hv = *(const float4*)&hidL[r][h][0];
        rwA[r][0] += hv.x * a;  rwB[r][0] += hv.x * bb;
        rwA[r][1] += hv.y * a;  rwB[r][1] += hv.y * bb;
        rwA[r][2] += hv.z * a;  rwB[r][2] += hv.z * bb;
        rwA[r][3] += hv.w * a;  rwB[r][3] += hv.w * bb;
      }
    }
    // ---- consume into A accumulators ----
    #pragma unroll
    for (int si = 0; si < 4; ++si) {
      float zz = zvL[si][0][fo];
      float vx = zvL[si][1][fo];
      float vy = zvL[si][2][fo];
      float vz = zvL[si][3][fo];
      #pragma unroll
      for (int r = 0; r < 4; ++r) {
        float4 ue = uenvL[r][si];
        float fv = zz + ue.x*vx + ue.y*vy + ue.z*vz;
        ac[0][r] += (rwA[r][si] * ue.w) * fv;
        float t = (rwB[r][si] * ue.w) * fv * SQRT3_F;
        ac[1][r] += t * ue.x;
        ac[2][r] += t * ue.y;
        ac[3][r] += t * ue.z;
      }
    }
    __syncthreads();
  }

  // combine h-halves, then atomically accumulate into Ag (raw, ungated)
  if (p == 1) {
    #pragma unroll
    for (int c = 0; c < 4; ++c)
      #pragma unroll
      for (int r = 0; r < 4; ++r)
        combL[c*4 + r][fo] = ac[c][r];
  }
  __syncthreads();
  if (p == 0) {
    #pragma unroll
    for (int r = 0; r < 4; ++r) {
      float* base = Ag + ((size_t)(b*NN + r0 + r)*4)*NF + fo;
      #pragma unroll
      for (int c = 0; c < 4; ++c)
        atomicAdd(base + c*NF, ac[c][r] + combL[c*4 + r][fo]);
    }
  }
}

// ---------------------------------------------------------------------------
// NODE: gate, mix GEMMs, z next layer, gate MLP, mbv, pos update.
// Also re-zeros its Ag slice for the next edge pass (replaces memset).
// ---------------------------------------------------------------------------
__global__ void node_kernel(float* __restrict__ Ag,
                            const float* __restrict__ cvt,
                            int layer, int last,
                            float* __restrict__ vec,
                            float* __restrict__ z,
                            float* __restrict__ pos_cur,
                            const int* __restrict__ flag,
                            void* __restrict__ out)
{
  int bn = blockIdx.x;
  int f  = threadIdx.x;   // 0..127
  __shared__ float Ash[4][NF];
  __shared__ float scs[NF];
  __shared__ float h16[16];
  __shared__ float red[2][4];

  // load raw A, zero it for next pass, apply correlation gate
  {
    float* Arow = Ag + (size_t)bn*4*NF;
    float a0 = Arow[0*NF + f];
    float a1 = Arow[1*NF + f];
    float a2 = Arow[2*NF + f];
    float a3 = Arow[3*NF + f];
    Arow[0*NF + f] = 0.f;
    Arow[1*NF + f] = 0.f;
    Arow[2*NF + f] = 0.f;
    Arow[3*NF + f] = 0.f;
    float n0 = a0*a0;
    float C1 = cvt[C1_OFF + (layer*4 + 0)*NF + f];
    float C2 = cvt[C2_OFF + (layer*4 + 0)*NF + f];
    float C3 = cvt[C3_OFF + (layer*4 + 0)*NF + f];
    float g0 = 1.0f + C1*n0 + C2*n0*n0 + C3*n0*n0*n0;
    float n1 = a1*a1 + a2*a2 + a3*a3;
    float D1 = cvt[C1_OFF + (layer*4 + 1)*NF + f];
    float D2 = cvt[C2_OFF + (layer*4 + 1)*NF + f];
    float D3 = cvt[C3_OFF + (layer*4 + 1)*NF + f];
    float g1 = 1.0f + D1*n1 + D2*n1*n1 + D3*n1*n1*n1;
    Ash[0][f] = a0 * g0;
    Ash[1][f] = a1 * g1;
    Ash[2][f] = a2 * g1;
    Ash[3][f] = a3 * g1;
  }
  __syncthreads();

  const float* M0 = cvt + M0_OFF + layer*NF*NF;
  const float* M1 = cvt + M1_OFF + layer*NF*NF;
  float sn = 0.f, v0 = 0.f, v1 = 0.f, v2 = 0.f;
  #pragma unroll 4
  for (int k = 0; k < NF; ++k) {
    float m0 = M0[k*NF + f];
    float m1 = M1[k*NF + f];
    sn += Ash[0][k] * m0;
    v0 += Ash[1][k] * m1;
    v1 += Ash[2][k] * m1;
    v2 += Ash[3][k] * m1;
  }
  scs[f] = sn;
  __syncthreads();

  // z for next layer
  if (!last) {
    const float* W = cvt + WN_OFF + (layer+1)*NF*NF;
    float acc = 0.f;
    #pragma unroll 8
    for (int k = 0; k < NF; ++k)
      acc += scs[k] * W[k*NF + f];
    z[bn*NF + f] = acc;
  }

  if (f < 16) {
    const float* G1 = cvt + G1_OFF + layer*NF*16;
    float acc = 0.f;
    #pragma unroll 8
    for (int k = 0; k < NF; ++k)
      acc += scs[k] * G1[k*16 + f];
    h16[f] = silu_f(acc);
  }
  __syncthreads();
  const float* G2 = cvt + G2_OFF + layer*16*NF;
  float gate = 0.f;
  #pragma unroll
  for (int j = 0; j < 16; ++j)
    gate += h16[j] * G2[j*NF + f];
  float gv = gate * cvt[WV_OFF + layer*NF + f];

  vec[((size_t)bn*3 + 0)*NF + f] = v0;
  vec[((size_t)bn*3 + 1)*NF + f] = v1;
  vec[((size_t)bn*3 + 2)*NF + f] = v2;

  float p0 = v0*gv, p1 = v1*gv, p2 = v2*gv;
  #pragma unroll
  for (int off = 32; off > 0; off >>= 1) {
    p0 += __shfl_down(p0, off, 64);
    p1 += __shfl_down(p1, off, 64);
    p2 += __shfl_down(p2, off, 64);
  }
  int wave = f >> 6;
  if ((f & 63) == 0) { red[wave][0] = p0; red[wave][1] = p1; red[wave][2] = p2; }
  __syncthreads();
  if (f == 0) {
    float m0 = red[0][0] + red[1][0];
    float m1 = red[0][1] + red[1][1];
    float m2 = red[0][2] + red[1][2];
    float px = pos_cur[bn*3+0] + m0;
    float py = pos_cur[bn*3+1] + m1;
    float pz = pos_cur[bn*3+2] + m2;
    pos_cur[bn*3+0] = px;
    pos_cur[bn*3+1] = py;
    pos_cur[bn*3+2] = pz;
    if (last) {
      float ox = px - cvt[POS_OFF + bn*3+0];
      float oy = py - cvt[POS_OFF + bn*3+1];
      float oz = pz - cvt[POS_OFF + bn*3+2];
      if (*flag) {
        bf16* o = (bf16*)out;
        o[bn*3+0] = __float2bfloat16(ox);
        o[bn*3+1] = __float2bfloat16(oy);
        o[bn*3+2] = __float2bfloat16(oz);
      } else {
        float* o = (float*)out;
        o[bn*3+0] = ox;
        o[bn*3+1] = oy;
        o[bn*3+2] = oz;
      }
    }
  }
}

// ---------------------------------------------------------------------------
extern "C" void kernel_launch(void* const* d_in, const int* in_sizes, int n_in,
                              void* d_out, int out_size, void* d_ws, size_t ws_size,
                              hipStream_t stream)
{
  (void)in_sizes; (void)n_in; (void)out_size; (void)ws_size;
  const int* nfeat = (const int*)d_in[1];

  float* ws      = (float*)d_ws;
  int*   flag    = (int*)ws;                  // 16 floats reserved
  float* cvt     = ws + 16;                   // CVT_TOTAL floats
  float* pos_cur = cvt + CVT_TOTAL;           // 1536
  float* z       = pos_cur + NB*NN*3;         // 65536
  float* vec     = z + NB*NN*NF;              // 196608
  float* Ag      = vec + NB*NN*3*NF;          // 262144
  float* env     = Ag + NB*NN*4*NF;           // 65536

  convert_kernel<<<256, 256, 0, stream>>>(
      d_in[0], d_in[2], d_in[3], d_in[4], d_in[5], d_in[6], d_in[7], d_in[8],
      d_in[9], d_in[10], d_in[11], d_in[12], d_in[13], d_in[14], d_in[15],
      d_in[16], flag, cvt);
  prep_kernel<<<NB*NN, NF, 0, stream>>>(cvt, nfeat, pos_cur, z, vec, env, Ag);
  for (int i = 0; i < NL; ++i) {
    edge_kernel<<<1024, 256, 0, stream>>>(pos_cur, z, vec, env, cvt, i, Ag);
    node_kernel<<<NB*NN, NF, 0, stream>>>(Ag, cvt, i, (i == NL-1) ? 1 : 0,
                                          vec, z, pos_cur, flag, d_out);
  }
}

// Round 7
// 244.310 us; speedup vs baseline: 1.9369x; 1.9369x over previous
//
#include <hip/hip_runtime.h>
#include <hip/hip_bf16.h>
#include <math.h>

#define NB 4
#define NN 128
#define NF 128
#define NS 5
#define NT 32
#define NL 2

typedef __hip_bfloat16 bf16;

__device__ __forceinline__ float b2f(const bf16 x) { return __bfloat162float(x); }
__device__ __forceinline__ float silu_f(float x) { return x / (1.0f + expf(-x)); }

#define PI_F 3.14159265358979323846f
#define SQRT3_F 1.7320508075688772f

// converted-weights region offsets (floats) within d_ws after the flag slot
#define POS_OFF 0
#define GF_OFF  1536
#define WE_OFF  1664
#define BE_OFF  6400
#define WR1_OFF 6528
#define BR1_OFF 6656
#define WR2_OFF 6784
#define WN_OFF  72320
#define C1_OFF  105088
#define C2_OFF  106112
#define C3_OFF  107136
#define M0_OFF  108160
#define M1_OFF  140928
#define G1_OFF  173696
#define G2_OFF  177792
#define WV_OFF  181888
#define CVT_TOTAL 182144

// ---------------------------------------------------------------------------
// convert (+ fused detect): each block locally decides bf16 vs f32 from the
// positions array, then converts its slice of all float inputs to f32.
// ---------------------------------------------------------------------------
__global__ void convert_kernel(
    const void* __restrict__ pos, const void* __restrict__ gf,
    const void* __restrict__ we,  const void* __restrict__ be,
    const void* __restrict__ wr1, const void* __restrict__ br1,
    const void* __restrict__ wr2, const void* __restrict__ wn,
    const void* __restrict__ c1,  const void* __restrict__ c2,
    const void* __restrict__ c3,  const void* __restrict__ m0,
    const void* __restrict__ m1,  const void* __restrict__ g1,
    const void* __restrict__ g2,  const void* __restrict__ wv,
    int* __restrict__ flag, float* __restrict__ dst)
{
  __shared__ int sbad;
  const int tid = threadIdx.x;
  if (tid == 0) sbad = 0;
  __syncthreads();
  {
    const bf16* p = (const bf16*)pos;
    int bad = 0;
    for (int i = tid; i < NB*NN*3; i += blockDim.x) {
      float v = b2f(p[i]);
      if (!(fabsf(v) <= 1024.0f)) bad = 1;   // NaN also fails
    }
    if (bad) sbad = 1;
  }
  __syncthreads();
  const int fl = sbad ? 0 : 1;               // 1 = bf16 inputs
  if (blockIdx.x == 0 && tid == 0) *flag = fl;

  const int stride = gridDim.x * blockDim.x;
  for (int i = blockIdx.x * blockDim.x + tid; i < CVT_TOTAL; i += stride) {
    const void* src; int j;
    if      (i < GF_OFF)  { src = pos; j = i - POS_OFF; }
    else if (i < WE_OFF)  { src = gf;  j = i - GF_OFF; }
    else if (i < BE_OFF)  { src = we;  j = i - WE_OFF; }
    else if (i < WR1_OFF) { src = be;  j = i - BE_OFF; }
    else if (i < BR1_OFF) { src = wr1; j = i - WR1_OFF; }
    else if (i < WR2_OFF) { src = br1; j = i - BR1_OFF; }
    else if (i < WN_OFF)  { src = wr2; j = i - WR2_OFF; }
    else if (i < C1_OFF)  { src = wn;  j = i - WN_OFF; }
    else if (i < C2_OFF)  { src = c1;  j = i - C1_OFF; }
    else if (i < C3_OFF)  { src = c2;  j = i - C2_OFF; }
    else if (i < M0_OFF)  { src = c3;  j = i - C3_OFF; }
    else if (i < M1_OFF)  { src = m0;  j = i - M0_OFF; }
    else if (i < G1_OFF)  { src = m1;  j = i - M1_OFF; }
    else if (i < G2_OFF)  { src = g1;  j = i - G1_OFF; }
    else if (i < WV_OFF)  { src = g2;  j = i - G2_OFF; }
    else                  { src = wv;  j = i - WV_OFF; }
    dst[i] = fl ? b2f(((const bf16*)src)[j]) : ((const float*)src)[j];
  }
}

// ---------------------------------------------------------------------------
// prep: env row, scal row (LDS only), z layer-0, vec=0, pos_cur, Ag=0.
// ---------------------------------------------------------------------------
__global__ void prep_kernel(
    const float* __restrict__ cvt, const int* __restrict__ nfeat,
    float* __restrict__ pos_cur, float* __restrict__ z,
    float* __restrict__ vec, float* __restrict__ env,
    float* __restrict__ Ag)
{
  const int bn = blockIdx.x;        // b*NN + n
  const int b  = bn >> 7;
  const int n  = bn & 127;
  const int f  = threadIdx.x;       // 0..127
  __shared__ float posB[NN*3];
  __shared__ float scs[NF];

  for (int i = f; i < NN*3; i += 128)
    posB[i] = cvt[POS_OFF + b*NN*3 + i];

  // scal row (LDS only)
  {
    int sp = nfeat[bn] - 1;
    float acc = cvt[WE_OFF + sp*NF + f] + cvt[BE_OFF + f];
    #pragma unroll 8
    for (int t = 0; t < NT; ++t)
      acc += cvt[GF_OFF + b*NT + t] * cvt[WE_OFF + (NS + t)*NF + f];
    scs[f] = acc;
  }
  __syncthreads();

  // env row (from initial positions)
  {
    float px = posB[n*3+0], py = posB[n*3+1], pz = posB[n*3+2];
    int s = f;
    float vx = px - posB[s*3+0];
    float vy = py - posB[s*3+1];
    float vz = pz - posB[s*3+2];
    float lng = sqrtf(vx*vx + vy*vy + vz*vz + 1e-12f);
    env[bn*NN + s] = (lng < 10.0f) ? 0.5f*(cosf(PI_F*lng*0.1f) + 1.0f) : 0.0f;
  }

  // z for layer 0
  {
    const float* W = cvt + WN_OFF;   // layer 0
    float acc = 0.f;
    #pragma unroll 8
    for (int k = 0; k < NF; ++k)
      acc += scs[k] * W[k*NF + f];
    z[bn*NF + f] = acc;
  }

  // vec = 0, Ag = 0
  vec[((size_t)bn*3 + 0)*NF + f] = 0.f;
  vec[((size_t)bn*3 + 1)*NF + f] = 0.f;
  vec[((size_t)bn*3 + 2)*NF + f] = 0.f;
  float* Arow = Ag + (size_t)bn*4*NF;
  #pragma unroll
  for (int c = 0; c < 4; ++c) Arow[c*NF + f] = 0.f;

  if (f < 3) pos_cur[bn*3 + f] = posB[n*3 + f];
}

// ---------------------------------------------------------------------------
// EDGE v5: grid = NB*32*8 = 1024 blocks (b, 4-receiver tile, 16-sender group)
// 256 threads = (p = h-half, fo = column). Both ell0/ell1 Wr2 columns in
// registers. launch_bounds(256,2): allocator keeps ~128 VGPRs (NO spill —
// (256,4) forced 64 VGPRs and 670 MB of scratch traffic, round 6). With 128
// VGPRs HW schedules 4 waves/SIMD = 4 blocks/CU on the 1024-block grid.
// ---------------------------------------------------------------------------
__global__ __launch_bounds__(256, 2)
void edge_kernel(const float* __restrict__ pos_cur,
                 const float* __restrict__ z,
                 const float* __restrict__ vec,
                 const float* __restrict__ env,
                 const float* __restrict__ cvt,
                 int layer, float* __restrict__ Ag)
{
  __shared__ float posL[NN*3];                 // 1.5 KB
  __shared__ float envL[4][16];                // this sender group
  __shared__ float w1L[64], b1L[64];
  __shared__ float zvL[4][4][NF];              // 8 KB
  __shared__ __align__(16) float hidL[4][64][4]; // 4 KB
  __shared__ __align__(16) float4 uenvL[4][4];
  __shared__ float combL[16][NF];              // 8 KB

  const int tid  = threadIdx.x;
  const int bidx = blockIdx.x;                 // b*256 + rt*8 + sg
  const int b    = bidx >> 8;
  const int rt   = (bidx >> 3) & 31;
  const int sg   = bidx & 7;
  const int r0   = rt * 4;
  const int sbase= sg * 16;
  const int p    = tid >> 7;
  const int fo   = tid & 127;

  for (int i = tid; i < NN*3; i += 256)
    posL[i] = pos_cur[b*NN*3 + i];
  if (tid < 64) {
    int rr = tid >> 4, j = tid & 15;
    envL[rr][j] = env[(b*NN + r0 + rr)*NN + sbase + j];
    w1L[tid] = cvt[WR1_OFF + layer*64 + tid];
    b1L[tid] = cvt[BR1_OFF + layer*64 + tid];
  }
  // Wr2 columns for both halves into registers
  float wA[32], wB[32];
  {
    const float* W2 = cvt + WR2_OFF + layer*64*512;
    #pragma unroll
    for (int hh = 0; hh < 32; ++hh) {
      wA[hh] = W2[(p*32 + hh)*512 + fo];        // ell0 column
      wB[hh] = W2[(p*32 + hh)*512 + 128 + fo];  // ell1 column
    }
  }
  float ac[4][4];
  #pragma unroll
  for (int c = 0; c < 4; ++c)
    #pragma unroll
    for (int r = 0; r < 4; ++r) ac[c][r] = 0.f;

  __syncthreads();

  const int rme = tid >> 6;
  const int hme = tid & 63;
  const float hrx = posL[(r0 + rme)*3 + 0];
  const float hry = posL[(r0 + rme)*3 + 1];
  const float hrz = posL[(r0 + rme)*3 + 2];
  const float w1v = w1L[hme], b1v = b1L[hme];

  for (int c0 = 0; c0 < 16; c0 += 4) {
    // ---- issue global loads first (hide under LDS math below) ----
    float stg[8];
    #pragma unroll
    for (int j = 0; j < 8; ++j) {
      int i = tid + j*256;
      int s = i >> 9, row = (i >> 7) & 3;
      int c = i & 127;
      int gs = b*NN + sbase + c0 + s;
      stg[j] = (row == 0) ? z[gs*NF + c]
                          : vec[((size_t)gs*3 + row - 1)*NF + c];
    }
    // ---- radial-hidden (LDS-only math) ----
    {
      float hv[4];
      #pragma unroll
      for (int si = 0; si < 4; ++si) {
        int s = sbase + c0 + si;
        float vx = hrx - posL[s*3 + 0];
        float vy = hry - posL[s*3 + 1];
        float vz = hrz - posL[s*3 + 2];
        float lng = sqrtf(vx*vx + vy*vy + vz*vz + 1e-12f);
        hv[si] = silu_f(lng * w1v + b1v);
      }
      *(float4*)&hidL[rme][hme][0] = make_float4(hv[0], hv[1], hv[2], hv[3]);
    }
    if (tid < 16) {
      int r = tid >> 2, si = tid & 3;
      int s = sbase + c0 + si;
      float vx = posL[(r0 + r)*3 + 0] - posL[s*3 + 0];
      float vy = posL[(r0 + r)*3 + 1] - posL[s*3 + 1];
      float vz = posL[(r0 + r)*3 + 2] - posL[s*3 + 2];
      float lng = sqrtf(vx*vx + vy*vy + vz*vz + 1e-12f);
      float inv = 1.0f / lng;
      float envw = (s == r0 + r) ? 0.f : envL[r][c0 + si] * 0.0625f;
      uenvL[r][si] = make_float4(vx*inv, vy*inv, vz*inv, envw);
    }
    // ---- commit staged z/vec to LDS ----
    #pragma unroll
    for (int j = 0; j < 8; ++j) {
      int i = tid + j*256;
      int s = i >> 9, row = (i >> 7) & 3, c = i & 127;
      zvL[s][row][c] = stg[j];
    }
    __syncthreads();

    // ---- rw partial dots (both column-halves per thread) ----
    float rwA[4][4], rwB[4][4];
    #pragma unroll
    for (int r = 0; r < 4; ++r)
      #pragma unroll
      for (int si = 0; si < 4; ++si) { rwA[r][si] = 0.f; rwB[r][si] = 0.f; }
    #pragma unroll
    for (int hh = 0; hh < 32; ++hh) {
      float a = wA[hh], bb = wB[hh];
      int h = p*32 + hh;
      #pragma unroll
      for (int r = 0; r < 4; ++r) {
        float4 hv = *(const float4*)&hidL[r][h][0];
        rwA[r][0] += hv.x * a;  rwB[r][0] += hv.x * bb;
        rwA[r][1] += hv.y * a;  rwB[r][1] += hv.y * bb;
        rwA[r][2] += hv.z * a;  rwB[r][2] += hv.z * bb;
        rwA[r][3] += hv.w * a;  rwB[r][3] += hv.w * bb;
      }
    }
    // ---- consume into A accumulators ----
    #pragma unroll
    for (int si = 0; si < 4; ++si) {
      float zz = zvL[si][0][fo];
      float vx = zvL[si][1][fo];
      float vy = zvL[si][2][fo];
      float vz = zvL[si][3][fo];
      #pragma unroll
      for (int r = 0; r < 4; ++r) {
        float4 ue = uenvL[r][si];
        float fv = zz + ue.x*vx + ue.y*vy + ue.z*vz;
        ac[0][r] += (rwA[r][si] * ue.w) * fv;
        float t = (rwB[r][si] * ue.w) * fv * SQRT3_F;
        ac[1][r] += t * ue.x;
        ac[2][r] += t * ue.y;
        ac[3][r] += t * ue.z;
      }
    }
    __syncthreads();
  }

  // combine h-halves, then atomically accumulate into Ag (raw, ungated)
  if (p == 1) {
    #pragma unroll
    for (int c = 0; c < 4; ++c)
      #pragma unroll
      for (int r = 0; r < 4; ++r)
        combL[c*4 + r][fo] = ac[c][r];
  }
  __syncthreads();
  if (p == 0) {
    #pragma unroll
    for (int r = 0; r < 4; ++r) {
      float* base = Ag + ((size_t)(b*NN + r0 + r)*4)*NF + fo;
      #pragma unroll
      for (int c = 0; c < 4; ++c)
        atomicAdd(base + c*NF, ac[c][r] + combL[c*4 + r][fo]);
    }
  }
}

// ---------------------------------------------------------------------------
// NODE: gate, mix GEMMs, z next layer, gate MLP, mbv, pos update.
// Also re-zeros its Ag slice for the next edge pass (replaces memset).
// ---------------------------------------------------------------------------
__global__ void node_kernel(float* __restrict__ Ag,
                            const float* __restrict__ cvt,
                            int layer, int last,
                            float* __restrict__ vec,
                            float* __restrict__ z,
                            float* __restrict__ pos_cur,
                            const int* __restrict__ flag,
                            void* __restrict__ out)
{
  int bn = blockIdx.x;
  int f  = threadIdx.x;   // 0..127
  __shared__ float Ash[4][NF];
  __shared__ float scs[NF];
  __shared__ float h16[16];
  __shared__ float red[2][4];

  // load raw A, zero it for next pass, apply correlation gate
  {
    float* Arow = Ag + (size_t)bn*4*NF;
    float a0 = Arow[0*NF + f];
    float a1 = Arow[1*NF + f];
    float a2 = Arow[2*NF + f];
    float a3 = Arow[3*NF + f];
    Arow[0*NF + f] = 0.f;
    Arow[1*NF + f] = 0.f;
    Arow[2*NF + f] = 0.f;
    Arow[3*NF + f] = 0.f;
    float n0 = a0*a0;
    float C1 = cvt[C1_OFF + (layer*4 + 0)*NF + f];
    float C2 = cvt[C2_OFF + (layer*4 + 0)*NF + f];
    float C3 = cvt[C3_OFF + (layer*4 + 0)*NF + f];
    float g0 = 1.0f + C1*n0 + C2*n0*n0 + C3*n0*n0*n0;
    float n1 = a1*a1 + a2*a2 + a3*a3;
    float D1 = cvt[C1_OFF + (layer*4 + 1)*NF + f];
    float D2 = cvt[C2_OFF + (layer*4 + 1)*NF + f];
    float D3 = cvt[C3_OFF + (layer*4 + 1)*NF + f];
    float g1 = 1.0f + D1*n1 + D2*n1*n1 + D3*n1*n1*n1;
    Ash[0][f] = a0 * g0;
    Ash[1][f] = a1 * g1;
    Ash[2][f] = a2 * g1;
    Ash[3][f] = a3 * g1;
  }
  __syncthreads();

  const float* M0 = cvt + M0_OFF + layer*NF*NF;
  const float* M1 = cvt + M1_OFF + layer*NF*NF;
  float sn = 0.f, v0 = 0.f, v1 = 0.f, v2 = 0.f;
  #pragma unroll 4
  for (int k = 0; k < NF; ++k) {
    float m0 = M0[k*NF + f];
    float m1 = M1[k*NF + f];
    sn += Ash[0][k] * m0;
    v0 += Ash[1][k] * m1;
    v1 += Ash[2][k] * m1;
    v2 += Ash[3][k] * m1;
  }
  scs[f] = sn;
  __syncthreads();

  // z for next layer
  if (!last) {
    const float* W = cvt + WN_OFF + (layer+1)*NF*NF;
    float acc = 0.f;
    #pragma unroll 8
    for (int k = 0; k < NF; ++k)
      acc += scs[k] * W[k*NF + f];
    z[bn*NF + f] = acc;
  }

  if (f < 16) {
    const float* G1 = cvt + G1_OFF + layer*NF*16;
    float acc = 0.f;
    #pragma unroll 8
    for (int k = 0; k < NF; ++k)
      acc += scs[k] * G1[k*16 + f];
    h16[f] = silu_f(acc);
  }
  __syncthreads();
  const float* G2 = cvt + G2_OFF + layer*16*NF;
  float gate = 0.f;
  #pragma unroll
  for (int j = 0; j < 16; ++j)
    gate += h16[j] * G2[j*NF + f];
  float gv = gate * cvt[WV_OFF + layer*NF + f];

  vec[((size_t)bn*3 + 0)*NF + f] = v0;
  vec[((size_t)bn*3 + 1)*NF + f] = v1;
  vec[((size_t)bn*3 + 2)*NF + f] = v2;

  float p0 = v0*gv, p1 = v1*gv, p2 = v2*gv;
  #pragma unroll
  for (int off = 32; off > 0; off >>= 1) {
    p0 += __shfl_down(p0, off, 64);
    p1 += __shfl_down(p1, off, 64);
    p2 += __shfl_down(p2, off, 64);
  }
  int wave = f >> 6;
  if ((f & 63) == 0) { red[wave][0] = p0; red[wave][1] = p1; red[wave][2] = p2; }
  __syncthreads();
  if (f == 0) {
    float m0 = red[0][0] + red[1][0];
    float m1 = red[0][1] + red[1][1];
    float m2 = red[0][2] + red[1][2];
    float px = pos_cur[bn*3+0] + m0;
    float py = pos_cur[bn*3+1] + m1;
    float pz = pos_cur[bn*3+2] + m2;
    pos_cur[bn*3+0] = px;
    pos_cur[bn*3+1] = py;
    pos_cur[bn*3+2] = pz;
    if (last) {
      float ox = px - cvt[POS_OFF + bn*3+0];
      float oy = py - cvt[POS_OFF + bn*3+1];
      float oz = pz - cvt[POS_OFF + bn*3+2];
      if (*flag) {
        bf16* o = (bf16*)out;
        o[bn*3+0] = __float2bfloat16(ox);
        o[bn*3+1] = __float2bfloat16(oy);
        o[bn*3+2] = __float2bfloat16(oz);
      } else {
        float* o = (float*)out;
        o[bn*3+0] = ox;
        o[bn*3+1] = oy;
        o[bn*3+2] = oz;
      }
    }
  }
}

// ---------------------------------------------------------------------------
extern "C" void kernel_launch(void* const* d_in, const int* in_sizes, int n_in,
                              void* d_out, int out_size, void* d_ws, size_t ws_size,
                              hipStream_t stream)
{
  (void)in_sizes; (void)n_in; (void)out_size; (void)ws_size;
  const int* nfeat = (const int*)d_in[1];

  float* ws      = (float*)d_ws;
  int*   flag    = (int*)ws;                  // 16 floats reserved
  float* cvt     = ws + 16;                   // CVT_TOTAL floats
  float* pos_cur = cvt + CVT_TOTAL;           // 1536
  float* z       = pos_cur + NB*NN*3;         // 65536
  float* vec     = z + NB*NN*NF;              // 196608
  float* Ag      = vec + NB*NN*3*NF;          // 262144
  float* env     = Ag + NB*NN*4*NF;           // 65536

  convert_kernel<<<256, 256, 0, stream>>>(
      d_in[0], d_in[2], d_in[3], d_in[4], d_in[5], d_in[6], d_in[7], d_in[8],
      d_in[9], d_in[10], d_in[11], d_in[12], d_in[13], d_in[14], d_in[15],
      d_in[16], flag, cvt);
  prep_kernel<<<NB*NN, NF, 0, stream>>>(cvt, nfeat, pos_cur, z, vec, env, Ag);
  for (int i = 0; i < NL; ++i) {
    edge_kernel<<<1024, 256, 0, stream>>>(pos_cur, z, vec, env, cvt, i, Ag);
    node_kernel<<<NB*NN, NF, 0, stream>>>(Ag, cvt, i, (i == NL-1) ? 1 : 0,
                                          vec, z, pos_cur, flag, d_out);
  }
}

// Round 9
// 243.680 us; speedup vs baseline: 1.9419x; 1.0026x over previous
//
#include <hip/hip_runtime.h>
#include <hip/hip_bf16.h>
#include <math.h>

#define NB 4
#define NN 128
#define NF 128
#define NS 5
#define NT 32
#define NL 2

typedef __hip_bfloat16 bf16;

__device__ __forceinline__ float b2f(const bf16 x) { return __bfloat162float(x); }
__device__ __forceinline__ float fast_rcp(float x) { return __builtin_amdgcn_rcpf(x); }
__device__ __forceinline__ float fast_rsq(float x) { return __builtin_amdgcn_rsqf(x); }
__device__ __forceinline__ float silu_fast(float x) { return x * fast_rcp(1.0f + __expf(-x)); }
__device__ __forceinline__ float ldf(const void* p, int i, int fl) {
  return fl ? b2f(((const bf16*)p)[i]) : ((const float*)p)[i];
}

#define PI_F 3.14159265358979323846f
#define SQRT3_F 1.7320508075688772f

// converted-weights region offsets (floats) within d_ws after the flag slot
#define POS_OFF 0
#define GF_OFF  1536
#define WE_OFF  1664
#define BE_OFF  6400
#define WR1_OFF 6528
#define BR1_OFF 6656
#define WR2_OFF 6784
#define WN_OFF  72320
#define C1_OFF  105088
#define C2_OFF  106112
#define C3_OFF  107136
#define M0_OFF  108160
#define M1_OFF  140928
#define G1_OFF  173696
#define G2_OFF  177792
#define WV_OFF  181888
#define CVT_TOTAL 182144

// ---------------------------------------------------------------------------
// prep_convert: 512 blocks x 256 threads. Each block:
//  - detects dtype locally (deterministic, all blocks agree),
//  - converts its slice of the cvt region,
//  - preps node row bn from RAW inputs (dual-dtype): env row, scal (LDS),
//    z layer-0, vec=0, Ag=0, pos_cur.
// ---------------------------------------------------------------------------
__global__ void prep_convert_kernel(
    const void* __restrict__ pos_raw, const int* __restrict__ nfeat,
    const void* __restrict__ gf,  const void* __restrict__ we,
    const void* __restrict__ be,  const void* __restrict__ wr1,
    const void* __restrict__ br1, const void* __restrict__ wr2,
    const void* __restrict__ wn,  const void* __restrict__ c1,
    const void* __restrict__ c2,  const void* __restrict__ c3,
    const void* __restrict__ m0,  const void* __restrict__ m1,
    const void* __restrict__ g1,  const void* __restrict__ g2,
    const void* __restrict__ wv,
    int* __restrict__ flag, float* __restrict__ cvt,
    float* __restrict__ pos_cur, float* __restrict__ z,
    float* __restrict__ vec, float* __restrict__ env,
    float* __restrict__ Ag)
{
  __shared__ float posB[NN*3];
  __shared__ float scs[NF];
  __shared__ int sbad;
  const int tid = threadIdx.x;
  const int bn  = blockIdx.x;        // node row, 0..511
  const int b   = bn >> 7;
  const int n   = bn & 127;

  // ---- local dtype detect ----
  if (tid == 0) sbad = 0;
  __syncthreads();
  {
    const bf16* p = (const bf16*)pos_raw;
    int bad = 0;
    for (int i = tid; i < NB*NN*3; i += 256) {
      float v = b2f(p[i]);
      if (!(fabsf(v) <= 1024.0f)) bad = 1;   // NaN also fails
    }
    if (bad) sbad = 1;
  }
  __syncthreads();
  const int fl = sbad ? 0 : 1;               // 1 = bf16 inputs
  if (bn == 0 && tid == 0) *flag = fl;

  // ---- convert this block's slice of cvt ----
  for (int i = bn*256 + tid; i < CVT_TOTAL; i += 512*256) {
    const void* src; int j;
    if      (i < GF_OFF)  { src = pos_raw; j = i - POS_OFF; }
    else if (i < WE_OFF)  { src = gf;  j = i - GF_OFF; }
    else if (i < BE_OFF)  { src = we;  j = i - WE_OFF; }
    else if (i < WR1_OFF) { src = be;  j = i - BE_OFF; }
    else if (i < BR1_OFF) { src = wr1; j = i - WR1_OFF; }
    else if (i < WR2_OFF) { src = br1; j = i - BR1_OFF; }
    else if (i < WN_OFF)  { src = wr2; j = i - WR2_OFF; }
    else if (i < C1_OFF)  { src = wn;  j = i - WN_OFF; }
    else if (i < C2_OFF)  { src = c1;  j = i - C1_OFF; }
    else if (i < C3_OFF)  { src = c2;  j = i - C2_OFF; }
    else if (i < M0_OFF)  { src = c3;  j = i - C3_OFF; }
    else if (i < M1_OFF)  { src = m0;  j = i - M0_OFF; }
    else if (i < G1_OFF)  { src = m1;  j = i - M1_OFF; }
    else if (i < G2_OFF)  { src = g1;  j = i - G1_OFF; }
    else if (i < WV_OFF)  { src = g2;  j = i - G2_OFF; }
    else                  { src = wv;  j = i - WV_OFF; }
    cvt[i] = fl ? b2f(((const bf16*)src)[j]) : ((const float*)src)[j];
  }

  // ---- prep row bn (raw dual-dtype reads) ----
  for (int i = tid; i < NN*3; i += 256)
    posB[i] = ldf(pos_raw, b*NN*3 + i, fl);
  if (tid < 128) {
    int sp = nfeat[bn] - 1;
    float acc = ldf(we, sp*NF + tid, fl) + ldf(be, tid, fl);
    #pragma unroll 8
    for (int t = 0; t < NT; ++t)
      acc += ldf(gf, b*NT + t, fl) * ldf(we, (NS + t)*NF + tid, fl);
    scs[tid] = acc;
  }
  __syncthreads();

  if (tid < 128) {
    const int f = tid;
    // env row (from initial positions)
    {
      float px = posB[n*3+0], py = posB[n*3+1], pz = posB[n*3+2];
      float vx = px - posB[f*3+0];
      float vy = py - posB[f*3+1];
      float vz = pz - posB[f*3+2];
      float lng = sqrtf(vx*vx + vy*vy + vz*vz + 1e-12f);
      env[bn*NN + f] = (lng < 10.0f) ? 0.5f*(cosf(PI_F*lng*0.1f) + 1.0f) : 0.0f;
    }
    // z layer-0 (raw Wnode, dual-dtype; uniform branch)
    {
      float acc = 0.f;
      if (fl) {
        const bf16* W = (const bf16*)wn;
        #pragma unroll 8
        for (int k = 0; k < NF; ++k) acc += scs[k] * b2f(W[k*NF + f]);
      } else {
        const float* W = (const float*)wn;
        #pragma unroll 8
        for (int k = 0; k < NF; ++k) acc += scs[k] * W[k*NF + f];
      }
      z[bn*NF + f] = acc;
    }
    // vec = 0, Ag = 0
    vec[((size_t)bn*3 + 0)*NF + f] = 0.f;
    vec[((size_t)bn*3 + 1)*NF + f] = 0.f;
    vec[((size_t)bn*3 + 2)*NF + f] = 0.f;
    float* Arow = Ag + (size_t)bn*4*NF;
    #pragma unroll
    for (int c = 0; c < 4; ++c) Arow[c*NF + f] = 0.f;
    if (f < 3) pos_cur[bn*3 + f] = posB[n*3 + f];
  }
}

// ---------------------------------------------------------------------------
// EDGE v6: grid = NB*32*8 = 1024 blocks (b, 4-receiver tile, 16-sender group)
// 256 threads = (p = h-half, fo = column). Both ell0/ell1 Wr2 columns in
// registers (sqrt3 folded into wB). Fast-math rsq/rcp/expf in per-edge chains.
// launch_bounds(256,2): allocator keeps ~128 VGPRs (NO spill — (256,4) forced
// 64 VGPRs and 670 MB of scratch traffic, round 6).
// ---------------------------------------------------------------------------
__global__ __launch_bounds__(256, 2)
void edge_kernel(const float* __restrict__ pos_cur,
                 const float* __restrict__ z,
                 const float* __restrict__ vec,
                 const float* __restrict__ env,
                 const float* __restrict__ cvt,
                 int layer, float* __restrict__ Ag)
{
  __shared__ float posL[NN*3];                 // 1.5 KB
  __shared__ float envL[4][16];                // this sender group
  __shared__ float w1L[64], b1L[64];
  __shared__ float zvL[4][4][NF];              // 8 KB
  __shared__ __align__(16) float hidL[4][64][4]; // 4 KB
  __shared__ __align__(16) float4 uenvL[4][4];
  __shared__ float combL[16][NF];              // 8 KB

  const int tid  = threadIdx.x;
  const int bidx = blockIdx.x;                 // b*256 + rt*8 + sg
  const int b    = bidx >> 8;
  const int rt   = (bidx >> 3) & 31;
  const int sg   = bidx & 7;
  const int r0   = rt * 4;
  const int sbase= sg * 16;
  const int p    = tid >> 7;
  const int fo   = tid & 127;

  for (int i = tid; i < NN*3; i += 256)
    posL[i] = pos_cur[b*NN*3 + i];
  if (tid < 64) {
    int rr = tid >> 4, j = tid & 15;
    envL[rr][j] = env[(b*NN + r0 + rr)*NN + sbase + j];
    w1L[tid] = cvt[WR1_OFF + layer*64 + tid];
    b1L[tid] = cvt[BR1_OFF + layer*64 + tid];
  }
  // Wr2 columns for both halves into registers (sqrt3 folded into wB)
  float wA[32], wB[32];
  {
    const float* W2 = cvt + WR2_OFF + layer*64*512;
    #pragma unroll
    for (int hh = 0; hh < 32; ++hh) {
      wA[hh] = W2[(p*32 + hh)*512 + fo];
      wB[hh] = W2[(p*32 + hh)*512 + 128 + fo] * SQRT3_F;
    }
  }
  float ac[4][4];
  #pragma unroll
  for (int c = 0; c < 4; ++c)
    #pragma unroll
    for (int r = 0; r < 4; ++r) ac[c][r] = 0.f;

  __syncthreads();

  const int rme = tid >> 6;
  const int hme = tid & 63;
  const float hrx = posL[(r0 + rme)*3 + 0];
  const float hry = posL[(r0 + rme)*3 + 1];
  const float hrz = posL[(r0 + rme)*3 + 2];
  const float w1v = w1L[hme], b1v = b1L[hme];

  for (int c0 = 0; c0 < 16; c0 += 4) {
    // ---- issue global loads first (hide under LDS math below) ----
    float stg[8];
    #pragma unroll
    for (int j = 0; j < 8; ++j) {
      int i = tid + j*256;
      int s = i >> 9, row = (i >> 7) & 3;
      int c = i & 127;
      int gs = b*NN + sbase + c0 + s;
      stg[j] = (row == 0) ? z[gs*NF + c]
                          : vec[((size_t)gs*3 + row - 1)*NF + c];
    }
    // ---- radial-hidden (fast math) ----
    {
      float hv[4];
      #pragma unroll
      for (int si = 0; si < 4; ++si) {
        int s = sbase + c0 + si;
        float vx = hrx - posL[s*3 + 0];
        float vy = hry - posL[s*3 + 1];
        float vz = hrz - posL[s*3 + 2];
        float d = vx*vx + vy*vy + vz*vz + 1e-12f;
        float lng = d * fast_rsq(d);
        hv[si] = silu_fast(lng * w1v + b1v);
      }
      *(float4*)&hidL[rme][hme][0] = make_float4(hv[0], hv[1], hv[2], hv[3]);
    }
    if (tid < 16) {
      int r = tid >> 2, si = tid & 3;
      int s = sbase + c0 + si;
      float vx = posL[(r0 + r)*3 + 0] - posL[s*3 + 0];
      float vy = posL[(r0 + r)*3 + 1] - posL[s*3 + 1];
      float vz = posL[(r0 + r)*3 + 2] - posL[s*3 + 2];
      float d = vx*vx + vy*vy + vz*vz + 1e-12f;
      float inv = fast_rsq(d);
      float envw = (s == r0 + r) ? 0.f : envL[r][c0 + si] * 0.0625f;
      uenvL[r][si] = make_float4(vx*inv, vy*inv, vz*inv, envw);
    }
    // ---- commit staged z/vec to LDS ----
    #pragma unroll
    for (int j = 0; j < 8; ++j) {
      int i = tid + j*256;
      int s = i >> 9, row = (i >> 7) & 3, c = i & 127;
      zvL[s][row][c] = stg[j];
    }
    __syncthreads();

    // ---- rw partial dots (both column-halves per thread) ----
    float rwA[4][4], rwB[4][4];
    #pragma unroll
    for (int r = 0; r < 4; ++r)
      #pragma unroll
      for (int si = 0; si < 4; ++si) { rwA[r][si] = 0.f; rwB[r][si] = 0.f; }
    #pragma unroll
    for (int hh = 0; hh < 32; ++hh) {
      float a = wA[hh], bb = wB[hh];
      int h = p*32 + hh;
      #pragma unroll
      for (int r = 0; r < 4; ++r) {
        float4 hv = *(const float4*)&hidL[r][h][0];
        rwA[r][0] += hv.x * a;  rwB[r][0] += hv.x * bb;
        rwA[r][1] += hv.y * a;  rwB[r][1] += hv.y * bb;
        rwA[r][2] += hv.z * a;  rwB[r][2] += hv.z * bb;
        rwA[r][3] += hv.w * a;  rwB[r][3] += hv.w * bb;
      }
    }
    // ---- consume into A accumulators ----
    #pragma unroll
    for (int si = 0; si < 4; ++si) {
      float zz = zvL[si][0][fo];
      float vx = zvL[si][1][fo];
      float vy = zvL[si][2][fo];
      float vz = zvL[si][3][fo];
      #pragma unroll
      for (int r = 0; r < 4; ++r) {
        float4 ue = uenvL[r][si];
        float fv = zz + ue.x*vx + ue.y*vy + ue.z*vz;
        ac[0][r] += (rwA[r][si] * ue.w) * fv;
        float t = (rwB[r][si] * ue.w) * fv;    // sqrt3 pre-folded into wB
        ac[1][r] += t * ue.x;
        ac[2][r] += t * ue.y;
        ac[3][r] += t * ue.z;
      }
    }
    __syncthreads();
  }

  // combine h-halves, then atomically accumulate into Ag (raw, ungated)
  if (p == 1) {
    #pragma unroll
    for (int c = 0; c < 4; ++c)
      #pragma unroll
      for (int r = 0; r < 4; ++r)
        combL[c*4 + r][fo] = ac[c][r];
  }
  __syncthreads();
  if (p == 0) {
    #pragma unroll
    for (int r = 0; r < 4; ++r) {
      float* base = Ag + ((size_t)(b*NN + r0 + r)*4)*NF + fo;
      #pragma unroll
      for (int c = 0; c < 4; ++c)
        atomicAdd(base + c*NF, ac[c][r] + combL[c*4 + r][fo]);
    }
  }
}

// ---------------------------------------------------------------------------
// NODE: gate, mix GEMMs, z next layer, gate MLP, mbv, pos update.
// Also re-zeros its Ag slice for the next edge pass.
// ---------------------------------------------------------------------------
__global__ void node_kernel(float* __restrict__ Ag,
                            const float* __restrict__ cvt,
                            int layer, int last,
                            float* __restrict__ vec,
                            float* __restrict__ z,
                            float* __restrict__ pos_cur,
                            const int* __restrict__ flag,
                            void* __restrict__ out)
{
  int bn = blockIdx.x;
  int f  = threadIdx.x;   // 0..127
  __shared__ float Ash[4][NF];
  __shared__ float scs[NF];
  __shared__ float h16[16];
  __shared__ float red[2][4];

  // load raw A, zero it for next pass, apply correlation gate
  {
    float* Arow = Ag + (size_t)bn*4*NF;
    float a0 = Arow[0*NF + f];
    float a1 = Arow[1*NF + f];
    float a2 = Arow[2*NF + f];
    float a3 = Arow[3*NF + f];
    Arow[0*NF + f] = 0.f;
    Arow[1*NF + f] = 0.f;
    Arow[2*NF + f] = 0.f;
    Arow[3*NF + f] = 0.f;
    float n0 = a0*a0;
    float C1 = cvt[C1_OFF + (layer*4 + 0)*NF + f];
    float C2 = cvt[C2_OFF + (layer*4 + 0)*NF + f];
    float C3 = cvt[C3_OFF + (layer*4 + 0)*NF + f];
    float g0 = 1.0f + C1*n0 + C2*n0*n0 + C3*n0*n0*n0;
    float n1 = a1*a1 + a2*a2 + a3*a3;
    float D1 = cvt[C1_OFF + (layer*4 + 1)*NF + f];
    float D2 = cvt[C2_OFF + (layer*4 + 1)*NF + f];
    float D3 = cvt[C3_OFF + (layer*4 + 1)*NF + f];
    float g1 = 1.0f + D1*n1 + D2*n1*n1 + D3*n1*n1*n1;
    Ash[0][f] = a0 * g0;
    Ash[1][f] = a1 * g1;
    Ash[2][f] = a2 * g1;
    Ash[3][f] = a3 * g1;
  }
  __syncthreads();

  const float* M0 = cvt + M0_OFF + layer*NF*NF;
  const float* M1 = cvt + M1_OFF + layer*NF*NF;
  float sn = 0.f, v0 = 0.f, v1 = 0.f, v2 = 0.f;
  #pragma unroll 4
  for (int k = 0; k < NF; ++k) {
    float m0 = M0[k*NF + f];
    float m1 = M1[k*NF + f];
    sn += Ash[0][k] * m0;
    v0 += Ash[1][k] * m1;
    v1 += Ash[2][k] * m1;
    v2 += Ash[3][k] * m1;
  }
  scs[f] = sn;
  __syncthreads();

  // z for next layer
  if (!last) {
    const float* W = cvt + WN_OFF + (layer+1)*NF*NF;
    float acc = 0.f;
    #pragma unroll 8
    for (int k = 0; k < NF; ++k)
      acc += scs[k] * W[k*NF + f];
    z[bn*NF + f] = acc;
  }

  if (f < 16) {
    const float* G1 = cvt + G1_OFF + layer*NF*16;
    float acc = 0.f;
    #pragma unroll 8
    for (int k = 0; k < NF; ++k)
      acc += scs[k] * G1[k*16 + f];
    h16[f] = silu_fast(acc);
  }
  __syncthreads();
  const float* G2 = cvt + G2_OFF + layer*16*NF;
  float gate = 0.f;
  #pragma unroll
  for (int j = 0; j < 16; ++j)
    gate += h16[j] * G2[j*NF + f];
  float gv = gate * cvt[WV_OFF + layer*NF + f];

  vec[((size_t)bn*3 + 0)*NF + f] = v0;
  vec[((size_t)bn*3 + 1)*NF + f] = v1;
  vec[((size_t)bn*3 + 2)*NF + f] = v2;

  float p0 = v0*gv, p1 = v1*gv, p2 = v2*gv;
  #pragma unroll
  for (int off = 32; off > 0; off >>= 1) {
    p0 += __shfl_down(p0, off, 64);
    p1 += __shfl_down(p1, off, 64);
    p2 += __shfl_down(p2, off, 64);
  }
  int wave = f >> 6;
  if ((f & 63) == 0) { red[wave][0] = p0; red[wave][1] = p1; red[wave][2] = p2; }
  __syncthreads();
  if (f == 0) {
    float m0 = red[0][0] + red[1][0];
    float m1 = red[0][1] + red[1][1];
    float m2 = red[0][2] + red[1][2];
    float px = pos_cur[bn*3+0] + m0;
    float py = pos_cur[bn*3+1] + m1;
    float pz = pos_cur[bn*3+2] + m2;
    pos_cur[bn*3+0] = px;
    pos_cur[bn*3+1] = py;
    pos_cur[bn*3+2] = pz;
    if (last) {
      float ox = px - cvt[POS_OFF + bn*3+0];
      float oy = py - cvt[POS_OFF + bn*3+1];
      float oz = pz - cvt[POS_OFF + bn*3+2];
      if (*flag) {
        bf16* o = (bf16*)out;
        o[bn*3+0] = __float2bfloat16(ox);
        o[bn*3+1] = __float2bfloat16(oy);
        o[bn*3+2] = __float2bfloat16(oz);
      } else {
        float* o = (float*)out;
        o[bn*3+0] = ox;
        o[bn*3+1] = oy;
        o[bn*3+2] = oz;
      }
    }
  }
}

// ---------------------------------------------------------------------------
extern "C" void kernel_launch(void* const* d_in, const int* in_sizes, int n_in,
                              void* d_out, int out_size, void* d_ws, size_t ws_size,
                              hipStream_t stream)
{
  (void)in_sizes; (void)n_in; (void)out_size; (void)ws_size;
  const int* nfeat = (const int*)d_in[1];

  float* ws      = (float*)d_ws;
  int*   flag    = (int*)ws;                  // 16 floats reserved
  float* cvt     = ws + 16;                   // CVT_TOTAL floats
  float* pos_cur = cvt + CVT_TOTAL;           // 1536
  float* z       = pos_cur + NB*NN*3;         // 65536
  float* vec     = z + NB*NN*NF;              // 196608
  float* Ag      = vec + NB*NN*3*NF;          // 262144
  float* env     = Ag + NB*NN*4*NF;           // 65536

  prep_convert_kernel<<<512, 256, 0, stream>>>(
      d_in[0], nfeat, d_in[2], d_in[3], d_in[4], d_in[5], d_in[6], d_in[7],
      d_in[8], d_in[9], d_in[10], d_in[11], d_in[12], d_in[13], d_in[14],
      d_in[15], d_in[16], flag, cvt, pos_cur, z, vec, env, Ag);
  for (int i = 0; i < NL; ++i) {
    edge_kernel<<<1024, 256, 0, stream>>>(pos_cur, z, vec, env, cvt, i, Ag);
    node_kernel<<<NB*NN, NF, 0, stream>>>(Ag, cvt, i, (i == NL-1) ? 1 : 0,
                                          vec, z, pos_cur, flag, d_out);
  }
}